// Round 14
// baseline (142.099 us; speedup 1.0000x reference)
//
#include <hip/hip_runtime.h>

#define Bn 2
#define Cn 512
#define Ln 4096
#define Hn 8
#define Dn 64

typedef _Float16 f16;
typedef _Float16 h8 __attribute__((ext_vector_type(8)));
typedef _Float16 h4 __attribute__((ext_vector_type(4)));
typedef float f32x4 __attribute__((ext_vector_type(4)));
typedef float f32x16 __attribute__((ext_vector_type(16)));

#define MFMA32(a, b, c) __builtin_amdgcn_mfma_f32_16x16x32_f16(a, b, c, 0, 0, 0)
#define MFMA3216(a, b, c) __builtin_amdgcn_mfma_f32_32x32x16_f16(a, b, c, 0, 0, 0)

// ---------------- kernel 1: X [B][C][L] f32 -> Xt [B][L][C] f16 ----------------
__global__ __launch_bounds__(256) void k_transpose(const float* __restrict__ X,
                                                   f16* __restrict__ Xt) {
  int bid = blockIdx.x;
  int b  = bid >> 9;
  int r  = bid & 511;
  int lt = r >> 3, ct = r & 7;
  int l0 = lt << 6, c0 = ct << 6;
  __shared__ f16 t[64][66];
  int tid = threadIdx.x;
  int lx = tid & 63, cg = tid >> 6;
  const float* xb = X + ((size_t)b * Cn) * Ln;
#pragma unroll
  for (int rr = 0; rr < 16; ++rr) {
    int cl = cg * 16 + rr;
    t[lx][cl] = (f16)xb[(size_t)(c0 + cl) * Ln + l0 + lx];
  }
  __syncthreads();
  f16* xo = Xt + ((size_t)b * Ln + l0) * Cn + c0;
  int cx = tid & 63, lg = tid >> 6;
#pragma unroll
  for (int rr = 0; rr < 16; ++rr) {
    int ll = lg * 16 + rr;
    xo[(size_t)ll * Cn + cx] = t[ll][cx];
  }
}

// ---------------- kernel 2: projection GEMM -> Q + chunk-major K/V ----------------
// Kc layout: [bh][tile=l/64][chunk=d/8][row=l%64][8 f16]   (tile stride 4096 f16)
// Vc layout: [bh][tile=l/64][chunk=(l%64)/8][row=d][8 f16] (j-chunked)
__global__ __launch_bounds__(256) void k_proj(const float* __restrict__ Wq,
                                              const float* __restrict__ Wm,
                                              const f16* __restrict__ Xt,
                                              f16* __restrict__ Qd,
                                              f16* __restrict__ Kc,
                                              f16* __restrict__ Vc) {
  int bid = blockIdx.x;
  int b = bid / 384;
  int r = bid % 384;
  int mt = r >> 5, nt = r & 31;
  int o0 = mt << 7, l0 = nt << 7;
  __shared__ f16 a_lds[128][40];
  __shared__ f16 b_lds[128][40];
  int tid = threadIdx.x;
  int lane = tid & 63, w = tid >> 6;
  int wr = w >> 1, wc = w & 1;
  f32x4 acc[4][4] = {};

  int sr = tid >> 1;
  int scg = (tid & 1) << 4;
  int o_s = o0 + sr;
  const float* wrow = (o_s < 512) ? (Wq + (size_t)o_s * Cn)
                                  : (Wm + (size_t)(o_s - 512) * Cn);
  const f16* xrow = Xt + ((size_t)b * Ln + l0 + sr) * Cn;

  float4 wa[4];
  h8 xbr[2];
#pragma unroll
  for (int i = 0; i < 4; ++i) wa[i] = *(const float4*)(wrow + scg + 4 * i);
#pragma unroll
  for (int i = 0; i < 2; ++i) xbr[i] = *(const h8*)(xrow + scg + 8 * i);

  for (int kt = 0; kt < 16; ++kt) {
    __syncthreads();
#pragma unroll
    for (int i = 0; i < 4; ++i) {
      float4 w4 = wa[i];
      h4 hh = { (f16)w4.x, (f16)w4.y, (f16)w4.z, (f16)w4.w };
      *(h4*)&a_lds[sr][scg + 4 * i] = hh;
    }
#pragma unroll
    for (int i = 0; i < 2; ++i)
      *(h8*)&b_lds[sr][scg + 8 * i] = xbr[i];
    if (kt < 15) {
      int c1 = (kt + 1) << 5;
#pragma unroll
      for (int i = 0; i < 4; ++i) wa[i] = *(const float4*)(wrow + c1 + scg + 4 * i);
#pragma unroll
      for (int i = 0; i < 2; ++i) xbr[i] = *(const h8*)(xrow + c1 + scg + 8 * i);
    }
    __syncthreads();

    h8 af[4], bf[4];
#pragma unroll
    for (int mi = 0; mi < 4; ++mi)
      af[mi] = *(const h8*)&a_lds[wr * 64 + mi * 16 + (lane & 15)][(lane >> 4) * 8];
#pragma unroll
    for (int ni = 0; ni < 4; ++ni)
      bf[ni] = *(const h8*)&b_lds[wc * 64 + ni * 16 + (lane & 15)][(lane >> 4) * 8];
#pragma unroll
    for (int mi = 0; mi < 4; ++mi)
#pragma unroll
      for (int ni = 0; ni < 4; ++ni)
        acc[mi][ni] = MFMA32(af[mi], bf[ni], acc[mi][ni]);
  }

  const float QSCALE = 0.18033688011112042f;   // 2^-3 * log2(e)
  int lrow = (lane >> 4) << 2;
  int lcol = lane & 15;
#pragma unroll
  for (int mi = 0; mi < 4; ++mi) {
    int ob = o0 + wr * 64 + mi * 16 + lrow;
#pragma unroll
    for (int ni = 0; ni < 4; ++ni) {
      int lc = l0 + wc * 64 + ni * 16 + lcol;
      f32x4 a = acc[mi][ni];
      if (ob < 512) {
        int h = ob >> 6, d = ob & 63;
        h4 hh = { (f16)(a[0] * QSCALE), (f16)(a[1] * QSCALE),
                  (f16)(a[2] * QSCALE), (f16)(a[3] * QSCALE) };
        *(h4*)&Qd[(((size_t)b * Hn + h) * Ln + lc) * Dn + d] = hh;
      } else if (ob < 1024) {
        int oc = ob - 512;
        int h = oc >> 6, d = oc & 63;       // d multiple of 4
        size_t off = (((size_t)(b * Hn + h) * 64 + (lc >> 6)) * 8 + (d >> 3)) * 512
                     + (size_t)(lc & 63) * 8 + (d & 7);
        h4 hh = { (f16)a[0], (f16)a[1], (f16)a[2], (f16)a[3] };
        *(h4*)&Kc[off] = hh;
      } else {
        int oc = ob - 1024;
        int h = oc >> 6, d = oc & 63;       // d multiple of 4
        size_t vb = (((size_t)(b * Hn + h) * 64 + (lc >> 6)) * 8 + ((lc & 63) >> 3)) * 512
                    + (size_t)(lc & 7);
#pragma unroll
        for (int rr = 0; rr < 4; ++rr)
          Vc[vb + (size_t)(d + rr) * 8] = (f16)a[rr];
      }
    }
  }
}

// ---------------- kernel 3: flash attention, barrier-free L2-direct ----------------
// grid 512 (XCD-swizzled), block = 8 waves, 2 KV-split groups (merge at end).
// K/V fragments read straight from L2-resident chunk-major buffers: no LDS
// staging, no barriers, no vmcnt in the loop. Waves free-run.
__global__ __launch_bounds__(512, 4) void k_attn(const f16* __restrict__ Qd,
                                                 const f16* __restrict__ Kc,
                                                 const f16* __restrict__ Vc,
                                                 const int* __restrict__ mask,
                                                 float* __restrict__ out) {
  int bid0 = blockIdx.x;
  int bid = (bid0 & 7) * 64 + (bid0 >> 3);   // T1: 64 blocks (2 bh) per XCD
  int bh = bid >> 5, ib = bid & 31;
  int b = bh >> 3, h = bh & 7;
  int tid = threadIdx.x;
  int lane = tid & 63, w = tid >> 6;
  int grp = w >> 2, wq = w & 3;
  int il = lane & 31, hi = lane >> 5;

  __shared__ __align__(16) float smem[4 * 64 * 33 + 256];   // merge scratch only

  int qb = ib * 128 + wq * 32;
  const f16* qp = Qd + ((size_t)bh * Ln + qb + il) * Dn;
  h8 qreg[4];
#pragma unroll
  for (int dt = 0; dt < 4; ++dt)
    qreg[dt] = *(const h8*)(qp + dt * 16 + hi * 8);

  const int* mbase = mask + (size_t)b * Ln;
  unsigned long long flags;
  {
    const int4* mp = (const int4*)mbase + lane * 16;
    int ac = 1;
#pragma unroll
    for (int q = 0; q < 16; ++q) { int4 v = mp[q]; ac &= v.x & v.y & v.z & v.w; }
    flags = __ballot(ac == 1);
  }

  // chunk-major bases for this bh + KV half
  const f16* kc = Kc + ((size_t)bh * 64 + grp * 32) * 4096;
  const f16* vc = Vc + ((size_t)bh * 64 + grp * 32) * 4096;

  f32x16 acc0 = {}, acc1 = {};  // O^T: col=i=il, row d = dt*32 + (r&3)+8*(r>>2)+4*hi
  f32x16 lacc = {};             // full-row P-sum via ones-MFMA
  const h8 vone = { (f16)1.f, (f16)1.f, (f16)1.f, (f16)1.f,
                    (f16)1.f, (f16)1.f, (f16)1.f, (f16)1.f };

  for (int t = 0; t < 32; ++t) {
    const f16* kt = kc + t * 4096;
    // ---- QK: fragments straight from L2 (512B contiguous per half-wave) ----
    f32x16 s0 = {}, s1 = {};
    __builtin_amdgcn_s_setprio(1);
#pragma unroll
    for (int dt = 0; dt < 4; ++dt) {
      const f16* kchunk = kt + (dt * 2 + hi) * 512 + il * 8;
      h8 ak0 = *(const h8*)kchunk;
      h8 ak1 = *(const h8*)(kchunk + 256);
      s0 = MFMA3216(ak0, qreg[dt], s0);
      s1 = MFMA3216(ak1, qreg[dt], s1);
    }
    __builtin_amdgcn_s_setprio(0);

    int T_ = grp * 32 + t;
    if (!((flags >> T_) & 1)) {          // rare masked path
#pragma unroll
      for (int r = 0; r < 16; ++r) {
        int j = T_ * 64 + (r & 3) + 8 * (r >> 2) + 4 * hi;
        if (!mbase[j])      s0[r] = -3.0e4f;
        if (!mbase[j + 32]) s1[r] = -3.0e4f;
      }
    }

    // ---- softmax (fixed base 0; cvt_pkrtz saturates, engagement needs logit>=16) ----
#pragma unroll
    for (int r = 0; r < 16; ++r) {
      s0[r] = __builtin_amdgcn_exp2f(s0[r]);
      s1[r] = __builtin_amdgcn_exp2f(s1[r]);
    }
    h8 pb[4];
    {
      float dw0[8], dw1[8];
#pragma unroll
      for (int r = 0; r < 16; r += 2) {
        dw0[r >> 1] = __builtin_bit_cast(float,
            __builtin_amdgcn_cvt_pkrtz(s0[r], s0[r + 1]));
        dw1[r >> 1] = __builtin_bit_cast(float,
            __builtin_amdgcn_cvt_pkrtz(s1[r], s1[r + 1]));
      }
#pragma unroll
      for (int jt = 0; jt < 4; ++jt) {
        float* dd = (jt < 2) ? dw0 : dw1;
        int base = (jt & 1) * 4;
        float a0 = dd[base + 0], b0 = dd[base + 2];
        float a1 = dd[base + 1], b1 = dd[base + 3];
        asm("v_permlane32_swap_b32 %0, %1" : "+v"(a0), "+v"(b0));
        asm("v_permlane32_swap_b32 %0, %1" : "+v"(a1), "+v"(b1));
        union { h8 v; float f[4]; } u;
        u.f[0] = a0; u.f[1] = a1; u.f[2] = b0; u.f[3] = b1;
        pb[jt] = u.v;
      }
    }

    // ---- lsum + PV: V fragments straight from L2 ----
    const f16* vt = vc + t * 4096;
    __builtin_amdgcn_s_setprio(1);
#pragma unroll
    for (int jt = 0; jt < 4; ++jt)
      lacc = MFMA3216(vone, pb[jt], lacc);
#pragma unroll
    for (int dt = 0; dt < 2; ++dt) {
#pragma unroll
      for (int jt = 0; jt < 4; ++jt) {
        h8 av = *(const h8*)(vt + (jt * 2 + hi) * 512 + (dt * 32 + il) * 8);
        if (dt == 0) acc0 = MFMA3216(av, pb[jt], acc0);
        else         acc1 = MFMA3216(av, pb[jt], acc1);
      }
    }
    __builtin_amdgcn_s_setprio(0);
  }

  float lsum = lacc[0];   // full-row sum (all regs equal)

  // ---- merge the two KV halves via LDS (padded stride-33) ----
  __syncthreads();
  if (grp == 1) {
    float* basep = smem + wq * (64 * 33) + lane * 33;
#pragma unroll
    for (int r = 0; r < 16; ++r) { basep[r] = acc0[r]; basep[16 + r] = acc1[r]; }
    smem[4 * 64 * 33 + wq * 64 + lane] = lsum;
  }
  __syncthreads();
  if (grp == 0) {
    float* basep = smem + wq * (64 * 33) + lane * 33;
    float lB = smem[4 * 64 * 33 + wq * 64 + lane];
    float linv = 1.f / fmaxf(lsum + lB, 1e-30f);
    size_t obase = ((size_t)b * Cn + h * 64) * Ln + qb + il;
#pragma unroll
    for (int r = 0; r < 16; ++r) {
      int d0 = (r & 3) + 8 * (r >> 2) + 4 * hi;
      out[obase + (size_t)d0 * Ln] = (acc0[r] + basep[r]) * linv;
      out[obase + (size_t)(d0 + 32) * Ln] = (acc1[r] + basep[16 + r]) * linv;
    }
  }
}

extern "C" void kernel_launch(void* const* d_in, const int* in_sizes, int n_in,
                              void* d_out, int out_size, void* d_ws, size_t ws_size,
                              hipStream_t stream) {
  const float* queries = (const float*)d_in[0];
  const int*   mask    = (const int*)d_in[1];
  const float* Wm      = (const float*)d_in[2];
  const float* Wq      = (const float*)d_in[3];
  float* out = (float*)d_out;
  char* ws = (char*)d_ws;
  f16* Xt = (f16*)(ws);
  f16* Qd = (f16*)(ws + 8388608);
  f16* Kc = (f16*)(ws + 16777216);
  f16* Vc = (f16*)(ws + 25165824);

  k_transpose<<<1024, 256, 0, stream>>>(queries, Xt);
  k_proj<<<768, 256, 0, stream>>>(Wq, Wm, Xt, Qd, Kc, Vc);
  k_attn<<<512, 512, 0, stream>>>(Qd, Kc, Vc, mask, out);
}

// Round 15
// 132.944 us; speedup vs baseline: 1.0689x; 1.0689x over previous
//
#include <hip/hip_runtime.h>

#define Bn 2
#define Cn 512
#define Ln 4096
#define Hn 8
#define Dn 64

typedef _Float16 f16;
typedef _Float16 h8 __attribute__((ext_vector_type(8)));
typedef _Float16 h4 __attribute__((ext_vector_type(4)));
typedef float f32x4 __attribute__((ext_vector_type(4)));
typedef float f32x16 __attribute__((ext_vector_type(16)));

#define MFMA32(a, b, c) __builtin_amdgcn_mfma_f32_16x16x32_f16(a, b, c, 0, 0, 0)
#define MFMA3216(a, b, c) __builtin_amdgcn_mfma_f32_32x32x16_f16(a, b, c, 0, 0, 0)
#define AS1(p) ((const __attribute__((address_space(1))) void*)(p))
#define AS3(p) ((__attribute__((address_space(3))) void*)(p))

// ---------------- kernel 1: X [B][C][L] f32 -> Xt [B][L][C] f16 ----------------
__global__ __launch_bounds__(256) void k_transpose(const float* __restrict__ X,
                                                   f16* __restrict__ Xt) {
  int bid = blockIdx.x;
  int b  = bid >> 9;
  int r  = bid & 511;
  int lt = r >> 3, ct = r & 7;
  int l0 = lt << 6, c0 = ct << 6;
  __shared__ f16 t[64][66];
  int tid = threadIdx.x;
  int lx = tid & 63, cg = tid >> 6;
  const float* xb = X + ((size_t)b * Cn) * Ln;
#pragma unroll
  for (int rr = 0; rr < 16; ++rr) {
    int cl = cg * 16 + rr;
    t[lx][cl] = (f16)xb[(size_t)(c0 + cl) * Ln + l0 + lx];
  }
  __syncthreads();
  f16* xo = Xt + ((size_t)b * Ln + l0) * Cn + c0;
  int cx = tid & 63, lg = tid >> 6;
#pragma unroll
  for (int rr = 0; rr < 16; ++rr) {
    int ll = lg * 16 + rr;
    xo[(size_t)ll * Cn + cx] = t[ll][cx];
  }
}

// ---------------- kernel 2: projection GEMM, reg-staged double buffer ----------------
__global__ __launch_bounds__(256) void k_proj(const float* __restrict__ Wq,
                                              const float* __restrict__ Wm,
                                              const f16* __restrict__ Xt,
                                              f16* __restrict__ Qd,
                                              f16* __restrict__ Kd,
                                              f16* __restrict__ Vv) {
  int bid = blockIdx.x;
  int b = bid / 384;
  int r = bid % 384;
  int mt = r >> 5, nt = r & 31;
  int o0 = mt << 7, l0 = nt << 7;
  __shared__ f16 a_lds[128][40];
  __shared__ f16 b_lds[128][40];
  int tid = threadIdx.x;
  int lane = tid & 63, w = tid >> 6;
  int wr = w >> 1, wc = w & 1;
  f32x4 acc[4][4] = {};

  int sr = tid >> 1;
  int scg = (tid & 1) << 4;
  int o_s = o0 + sr;
  const float* wrow = (o_s < 512) ? (Wq + (size_t)o_s * Cn)
                                  : (Wm + (size_t)(o_s - 512) * Cn);
  const f16* xrow = Xt + ((size_t)b * Ln + l0 + sr) * Cn;

  float4 wa[4];
  h8 xbr[2];
#pragma unroll
  for (int i = 0; i < 4; ++i) wa[i] = *(const float4*)(wrow + scg + 4 * i);
#pragma unroll
  for (int i = 0; i < 2; ++i) xbr[i] = *(const h8*)(xrow + scg + 8 * i);

  for (int kt = 0; kt < 16; ++kt) {
    __syncthreads();
#pragma unroll
    for (int i = 0; i < 4; ++i) {
      float4 w4 = wa[i];
      h4 hh = { (f16)w4.x, (f16)w4.y, (f16)w4.z, (f16)w4.w };
      *(h4*)&a_lds[sr][scg + 4 * i] = hh;
    }
#pragma unroll
    for (int i = 0; i < 2; ++i)
      *(h8*)&b_lds[sr][scg + 8 * i] = xbr[i];
    if (kt < 15) {
      int c1 = (kt + 1) << 5;
#pragma unroll
      for (int i = 0; i < 4; ++i) wa[i] = *(const float4*)(wrow + c1 + scg + 4 * i);
#pragma unroll
      for (int i = 0; i < 2; ++i) xbr[i] = *(const h8*)(xrow + c1 + scg + 8 * i);
    }
    __syncthreads();

    h8 af[4], bf[4];
#pragma unroll
    for (int mi = 0; mi < 4; ++mi)
      af[mi] = *(const h8*)&a_lds[wr * 64 + mi * 16 + (lane & 15)][(lane >> 4) * 8];
#pragma unroll
    for (int ni = 0; ni < 4; ++ni)
      bf[ni] = *(const h8*)&b_lds[wc * 64 + ni * 16 + (lane & 15)][(lane >> 4) * 8];
#pragma unroll
    for (int mi = 0; mi < 4; ++mi)
#pragma unroll
      for (int ni = 0; ni < 4; ++ni)
        acc[mi][ni] = MFMA32(af[mi], bf[ni], acc[mi][ni]);
  }

  const float QSCALE = 0.18033688011112042f;   // 2^-3 * log2(e)
  int lrow = (lane >> 4) << 2;
  int lcol = lane & 15;
#pragma unroll
  for (int mi = 0; mi < 4; ++mi) {
    int ob = o0 + wr * 64 + mi * 16 + lrow;
#pragma unroll
    for (int ni = 0; ni < 4; ++ni) {
      int lc = l0 + wc * 64 + ni * 16 + lcol;
      f32x4 a = acc[mi][ni];
      if (ob < 512) {
        int h = ob >> 6, d = ob & 63;
        h4 hh = { (f16)(a[0] * QSCALE), (f16)(a[1] * QSCALE),
                  (f16)(a[2] * QSCALE), (f16)(a[3] * QSCALE) };
        *(h4*)&Qd[(((size_t)b * Hn + h) * Ln + lc) * Dn + d] = hh;
      } else if (ob < 1024) {
        int oc = ob - 512;
        int h = oc >> 6, d = oc & 63;
        h4 hh = { (f16)a[0], (f16)a[1], (f16)a[2], (f16)a[3] };
        *(h4*)&Kd[(((size_t)b * Hn + h) * Ln + lc) * Dn + d] = hh;
      } else {
        int oc = ob - 1024;
#pragma unroll
        for (int rr = 0; rr < 4; ++rr)
          Vv[((size_t)b * Cn + oc + rr) * Ln + lc] = (f16)a[rr];
      }
    }
  }
}

// ---------------- kernel 3: flash attention, phase-staggered groups (R11 best: 108.5 us) ----------------
// grid 512 (XCD-swizzled), block = 8 waves, 2 KV-split groups, 2-deep LDS dbuf.
// Group 0 body: QK(t) -> SM_PV(t). Group 1 body: SM_PV(t-1) -> QK(t) (carries S).
// ALL staging strictly post-barrier (R10 race lesson: 2-deep parity (t+1)&1 == (t-1)&1).
__global__ __launch_bounds__(512, 4) void k_attn(const f16* __restrict__ Qd,
                                                 const f16* __restrict__ Kd,
                                                 const f16* __restrict__ Vv,
                                                 const int* __restrict__ mask,
                                                 float* __restrict__ out) {
  int bid0 = blockIdx.x;
  int bid = (bid0 & 7) * 64 + (bid0 >> 3);   // T1: 64 blocks (2 bh) per XCD
  int bh = bid >> 5, ib = bid & 31;
  int b = bh >> 3, h = bh & 7;
  int tid = threadIdx.x;
  int lane = tid & 63, w = tid >> 6;
  int grp = w >> 2, wq = w & 3;
  int il = lane & 31, hi = lane >> 5;

  __shared__ __align__(16) f16 smem[8 * 4096];
#define KBUF(g, bi) (&smem[(((g) * 2 + (bi))) * 4096])
#define VBUF(g, bi) (&smem[((4 + (g) * 2 + (bi))) * 4096])

  int qb = ib * 128 + wq * 32;
  const f16* qp = Qd + ((size_t)bh * Ln + qb + il) * Dn;
  h8 qreg[4];
#pragma unroll
  for (int dt = 0; dt < 4; ++dt)
    qreg[dt] = *(const h8*)(qp + dt * 16 + hi * 8);

  const int* mbase = mask + (size_t)b * Ln;
  unsigned long long flags;
  {
    const int4* mp = (const int4*)mbase + lane * 16;
    int ac = 1;
#pragma unroll
    for (int q = 0; q < 16; ++q) { int4 v = mp[q]; ac &= v.x & v.y & v.z & v.w; }
    flags = __ballot(ac == 1);
  }

  const f16* kbase = Kd + (size_t)bh * Ln * Dn + (size_t)grp * 32 * 4096;
  const f16* vbase = Vv + ((size_t)b * Cn + h * 64) * Ln + grp * 32 * 64;
  int koff[2], voff[2];
#pragma unroll
  for (int q = 0; q < 2; ++q) {
    int rr = wq * 16 + q * 8 + (lane >> 3);
    int swz = (lane & 7) ^ (rr & 7);
    koff[q] = rr * 64 + swz * 8;
    voff[q] = rr * Ln + swz * 8;
  }

#define STAGE_K(bi, t)                                                          \
  {                                                                             \
    _Pragma("unroll")                                                           \
    for (int q = 0; q < 2; ++q)                                                 \
      __builtin_amdgcn_global_load_lds(AS1(kbase + (size_t)(t) * 4096 + koff[q]),\
                                       AS3(KBUF(grp, bi) + (wq * 16 + q * 8) * 64),\
                                       16, 0, 0);                               \
  }
#define STAGE_V(bi, t)                                                          \
  {                                                                             \
    _Pragma("unroll")                                                           \
    for (int q = 0; q < 2; ++q)                                                 \
      __builtin_amdgcn_global_load_lds(AS1(vbase + (size_t)(t) * 64 + voff[q]), \
                                       AS3(VBUF(grp, bi) + (wq * 16 + q * 8) * 64),\
                                       16, 0, 0);                               \
  }

#define PACK_PB(S0_, S1_, DW0_, DW1_, PB_)                                      \
  {                                                                             \
    _Pragma("unroll")                                                           \
    for (int r = 0; r < 16; r += 2) {                                           \
      DW0_[r >> 1] = __builtin_bit_cast(float,                                  \
          __builtin_amdgcn_cvt_pkrtz(S0_[r], S0_[r + 1]));                      \
      DW1_[r >> 1] = __builtin_bit_cast(float,                                  \
          __builtin_amdgcn_cvt_pkrtz(S1_[r], S1_[r + 1]));                      \
    }                                                                           \
    _Pragma("unroll")                                                           \
    for (int jt = 0; jt < 4; ++jt) {                                            \
      float* dd = (jt < 2) ? DW0_ : DW1_;                                       \
      int base = (jt & 1) * 4;                                                  \
      float a0 = dd[base + 0], b0 = dd[base + 2];                               \
      float a1 = dd[base + 1], b1 = dd[base + 3];                               \
      asm("v_permlane32_swap_b32 %0, %1" : "+v"(a0), "+v"(b0));                 \
      asm("v_permlane32_swap_b32 %0, %1" : "+v"(a1), "+v"(b1));                 \
      union { h8 v; float f[4]; } u;                                            \
      u.f[0] = a0; u.f[1] = a1; u.f[2] = b0; u.f[3] = b1;                       \
      PB_[jt] = u.v;                                                            \
    }                                                                           \
  }

  f32x16 acc0 = {}, acc1 = {};  // O^T: col=i=il, row d = dt*32 + (r&3)+8*(r>>2)+4*hi
  float mrow = 0.f;             // fixed base point; bumped only by overflow gate
  float lsum = 0.f;             // half-row sum (merged across hi at epilogue)
  int swz7 = il & 7;

// QK(t): 8 MFMA on K(t) -> S regs (mask fix folded in)
#define QK(t_, S0_, S1_)                                                        \
  {                                                                             \
    const f16* kl_ = KBUF(grp, (t_) & 1);                                       \
    f32x16 z0 = {}, z1 = {};                                                    \
    __builtin_amdgcn_s_setprio(1);                                              \
    _Pragma("unroll")                                                           \
    for (int dt = 0; dt < 4; ++dt) {                                            \
      int c = ((dt * 2 + hi) ^ swz7) << 3;                                      \
      h8 ak0 = *(const h8*)&kl_[il * 64 + c];                                   \
      h8 ak1 = *(const h8*)&kl_[(32 + il) * 64 + c];                            \
      z0 = MFMA3216(ak0, qreg[dt], z0);                                         \
      z1 = MFMA3216(ak1, qreg[dt], z1);                                         \
    }                                                                           \
    __builtin_amdgcn_s_setprio(0);                                              \
    int T_ = grp * 32 + (t_);                                                   \
    if (!((flags >> T_) & 1)) {                                                 \
      _Pragma("unroll")                                                         \
      for (int r = 0; r < 16; ++r) {                                            \
        int j = T_ * 64 + (r & 3) + 8 * (r >> 2) + 4 * hi;                      \
        if (!mbase[j])      z0[r] = -3.0e4f;                                    \
        if (!mbase[j + 32]) z1[r] = -3.0e4f;                                    \
      }                                                                         \
    }                                                                           \
    S0_ = z0; S1_ = z1;                                                         \
  }

// SM_PV(t): softmax on S, then PV on V(t). Consumes S.
#define SM_PV(t_, S0_, S1_)                                                     \
  {                                                                             \
    _Pragma("unroll")                                                           \
    for (int r = 0; r < 16; ++r) {                                              \
      S0_[r] = __builtin_amdgcn_exp2f(S0_[r] - mrow);                           \
      S1_[r] = __builtin_amdgcn_exp2f(S1_[r] - mrow);                           \
    }                                                                           \
    float dw0[8], dw1[8];                                                       \
    h8 pb[4];                                                                   \
    PACK_PB(S0_, S1_, dw0, dw1, pb);                                            \
    float rs;                                                                   \
    {                                                                           \
      float a0 = (S0_[0] + S0_[1]) + (S0_[2] + S0_[3]);                         \
      float a1 = (S0_[4] + S0_[5]) + (S0_[6] + S0_[7]);                         \
      float a2 = (S0_[8] + S0_[9]) + (S0_[10] + S0_[11]);                       \
      float a3 = (S0_[12] + S0_[13]) + (S0_[14] + S0_[15]);                     \
      float a4 = (S1_[0] + S1_[1]) + (S1_[2] + S1_[3]);                         \
      float a5 = (S1_[4] + S1_[5]) + (S1_[6] + S1_[7]);                         \
      float a6 = (S1_[8] + S1_[9]) + (S1_[10] + S1_[11]);                       \
      float a7 = (S1_[12] + S1_[13]) + (S1_[14] + S1_[15]);                     \
      rs = ((a0 + a1) + (a2 + a3)) + ((a4 + a5) + (a6 + a7));                   \
    }                                                                           \
    if (__any(rs > 8192.f)) {  /* overflow gate: ~never, exact pow2 rescale */  \
      float mxp = fmaxf(                                                        \
        fmaxf(fmaxf(fmaxf(S0_[0], S0_[1]), fmaxf(S0_[2], S0_[3])),              \
              fmaxf(fmaxf(S0_[4], S0_[5]), fmaxf(S0_[6], S0_[7]))),             \
        fmaxf(fmaxf(fmaxf(S0_[8], S0_[9]), fmaxf(S0_[10], S0_[11])),            \
              fmaxf(fmaxf(S0_[12], S0_[13]), fmaxf(S0_[14], S0_[15]))));        \
      float mxq = fmaxf(                                                        \
        fmaxf(fmaxf(fmaxf(S1_[0], S1_[1]), fmaxf(S1_[2], S1_[3])),              \
              fmaxf(fmaxf(S1_[4], S1_[5]), fmaxf(S1_[6], S1_[7]))),             \
        fmaxf(fmaxf(fmaxf(S1_[8], S1_[9]), fmaxf(S1_[10], S1_[11])),            \
              fmaxf(fmaxf(S1_[12], S1_[13]), fmaxf(S1_[14], S1_[15]))));        \
      mxp = fmaxf(mxp, mxq);                                                    \
      mxp = fmaxf(mxp, __shfl_xor(mxp, 32));                                    \
      int e = (((__builtin_bit_cast(int, mxp) >> 23) & 255) - 127) - 3;         \
      float sc = __builtin_bit_cast(float, (127 - e) << 23);  /* 2^-e exact */  \
      mrow += (float)e;                                                         \
      _Pragma("unroll")                                                         \
      for (int r = 0; r < 16; ++r) {                                            \
        S0_[r] *= sc; S1_[r] *= sc;                                             \
        acc0[r] *= sc; acc1[r] *= sc;                                           \
      }                                                                         \
      lsum *= sc; rs *= sc;                                                     \
      PACK_PB(S0_, S1_, dw0, dw1, pb);                                          \
    }                                                                           \
    lsum += rs;                                                                 \
    const f16* vl_ = VBUF(grp, (t_) & 1);                                       \
    __builtin_amdgcn_s_setprio(1);                                              \
    _Pragma("unroll")                                                           \
    for (int dt = 0; dt < 2; ++dt) {                                            \
      int rv = dt * 32 + il;                                                    \
      _Pragma("unroll")                                                         \
      for (int jt = 0; jt < 4; ++jt) {                                          \
        h8 av = *(const h8*)&vl_[rv * 64 + (((jt * 2 + hi) ^ swz7) << 3)];      \
        if (dt == 0) acc0 = MFMA3216(av, pb[jt], acc0);                         \
        else         acc1 = MFMA3216(av, pb[jt], acc1);                         \
      }                                                                         \
    }                                                                           \
    __builtin_amdgcn_s_setprio(0);                                              \
  }

#define VM(n) asm volatile("s_waitcnt vmcnt(" n ")" ::: "memory")
#define BAR() __builtin_amdgcn_s_barrier()

  f32x16 sP0, sP1;

  if (grp == 0) {
    // ---- group 0: QK(t) then SM_PV(t); stage K(t+2),V(t+2) post-barrier. ----
    STAGE_K(0, 0); STAGE_V(0, 0);
    STAGE_K(1, 1); STAGE_V(1, 1);
    for (int t = 0; t < 31; ++t) {
      VM("4"); BAR();
      QK(t, sP0, sP1);
      SM_PV(t, sP0, sP1);
      BAR();
      if (t < 30) { STAGE_K(t & 1, t + 2); STAGE_V(t & 1, t + 2); }
    }
    VM("0"); BAR();
    QK(31, sP0, sP1);
    SM_PV(31, sP0, sP1);
    BAR();
  } else {
    // ---- group 1: SM_PV(t-1) then QK(t); ALL stages post-barrier. ----
    STAGE_V(0, 0); STAGE_K(0, 0);
    STAGE_V(1, 1); STAGE_K(1, 1);
    // body 0 (no SM_PV yet): need K(0) -> oldest 4 of {V0,K0,V1,K1}
    VM("4"); BAR();
    QK(0, sP0, sP1);
    BAR();
    STAGE_K(0, 2);
    // body 1: need V(0),K(1) -> leave only K(2) in flight
    VM("2"); BAR();
    SM_PV(0, sP0, sP1);
    QK(1, sP0, sP1);
    BAR();
    STAGE_K(1, 3); STAGE_V(0, 2);
    // bodies 2..30: need K(t),V(t-1); in flight also K(t+1),V(t)
    for (int t = 2; t <= 30; ++t) {
      VM("4"); BAR();
      SM_PV(t - 1, sP0, sP1);
      QK(t, sP0, sP1);
      BAR();
      if (t < 30) STAGE_K(t & 1, t + 2);
      STAGE_V((t + 1) & 1, t + 1);
    }
    // body 31: need K(31),V(30); leave V(31) in flight
    VM("2"); BAR();
    SM_PV(30, sP0, sP1);
    QK(31, sP0, sP1);
    BAR();
    VM("0");
    SM_PV(31, sP0, sP1);
  }

  // full-row lsum (lanes i and i+32 hold halves)
  lsum += __shfl_xor(lsum, 32);

  // ---- merge the two KV halves via LDS (padded stride-33) ----
  __syncthreads();
  float* shf = (float*)smem;
  if (grp == 1) {
    float* basep = shf + wq * (64 * 33) + lane * 33;
#pragma unroll
    for (int r = 0; r < 16; ++r) { basep[r] = acc0[r]; basep[16 + r] = acc1[r]; }
    float* ml = shf + 4 * 64 * 33 + (wq * 64 + lane) * 2;
    ml[0] = mrow; ml[1] = lsum;
  }
  __syncthreads();
  if (grp == 0) {
    float* basep = shf + wq * (64 * 33) + lane * 33;
    float* ml = shf + 4 * 64 * 33 + (wq * 64 + lane) * 2;
    float mB = ml[0], lB = ml[1];
    float M = fmaxf(mrow, mB);
    float wA = __builtin_amdgcn_exp2f(mrow - M);
    float wB = __builtin_amdgcn_exp2f(mB - M);
    float linv = 1.f / fmaxf(lsum * wA + lB * wB, 1e-30f);
    float fA = wA * linv, fB = wB * linv;
    size_t obase = ((size_t)b * Cn + h * 64) * Ln + qb + il;
#pragma unroll
    for (int r = 0; r < 16; ++r) {
      int d0 = (r & 3) + 8 * (r >> 2) + 4 * hi;
      out[obase + (size_t)d0 * Ln] = acc0[r] * fA + basep[r] * fB;
      out[obase + (size_t)(d0 + 32) * Ln] = acc1[r] * fA + basep[16 + r] * fB;
    }
  }
}

extern "C" void kernel_launch(void* const* d_in, const int* in_sizes, int n_in,
                              void* d_out, int out_size, void* d_ws, size_t ws_size,
                              hipStream_t stream) {
  const float* queries = (const float*)d_in[0];
  const int*   mask    = (const int*)d_in[1];
  const float* Wm      = (const float*)d_in[2];
  const float* Wq      = (const float*)d_in[3];
  float* out = (float*)d_out;
  char* ws = (char*)d_ws;
  f16* Xt = (f16*)(ws);
  f16* Qd = (f16*)(ws + 8388608);
  f16* Kd = (f16*)(ws + 16777216);
  f16* Vv = (f16*)(ws + 25165824);

  k_transpose<<<1024, 256, 0, stream>>>(queries, Xt);
  k_proj<<<768, 256, 0, stream>>>(Wq, Wm, Xt, Qd, Kd, Vv);
  k_attn<<<512, 512, 0, stream>>>(Qd, Kd, Vv, mask, out);
}

// Round 16
// 132.608 us; speedup vs baseline: 1.0716x; 1.0025x over previous
//
#include <hip/hip_runtime.h>

#define Bn 2
#define Cn 512
#define Ln 4096
#define Hn 8
#define Dn 64

typedef _Float16 f16;
typedef _Float16 h8 __attribute__((ext_vector_type(8)));
typedef _Float16 h4 __attribute__((ext_vector_type(4)));
typedef _Float16 h2 __attribute__((ext_vector_type(2)));
typedef float f32x4 __attribute__((ext_vector_type(4)));
typedef float f32x16 __attribute__((ext_vector_type(16)));

#define MFMA32(a, b, c) __builtin_amdgcn_mfma_f32_16x16x32_f16(a, b, c, 0, 0, 0)
#define MFMA3216(a, b, c) __builtin_amdgcn_mfma_f32_32x32x16_f16(a, b, c, 0, 0, 0)
#define AS1(p) ((const __attribute__((address_space(1))) void*)(p))
#define AS3(p) ((__attribute__((address_space(3))) void*)(p))

// ---------------- kernel 1: X [B][C][L] f32 -> Xt [B][L][C] f16 (vectorized) ----------------
// Loads: float4 over l (16B/lane). LDS: h2 paired-column writes (full dword),
// h4 reads ([64][68] keeps 8B row alignment). Stores: h8 (lanes 0-3 = 64B contig).
__global__ __launch_bounds__(256) void k_transpose(const float* __restrict__ X,
                                                   f16* __restrict__ Xt) {
  int bid = blockIdx.x;
  int b  = bid >> 9;
  int r  = bid & 511;
  int lt = r >> 3, ct = r & 7;
  int l0 = lt << 6, c0 = ct << 6;
  __shared__ f16 t[64][68];          // row stride 136B: 8B-aligned, odd dword stride
  int tid = threadIdx.x;

  int lq = tid & 15;                 // float4 slot along l
  int ch = tid >> 4;                 // c-pair group 0..15
  const float* xb = X + ((size_t)b * Cn + c0) * Ln + l0 + lq * 4;
#pragma unroll
  for (int i = 0; i < 2; ++i) {
    int cc = (ch + 16 * i) * 2;      // even column
    float4 va = *(const float4*)(xb + (size_t)cc * Ln);
    float4 vb = *(const float4*)(xb + (size_t)(cc + 1) * Ln);
    h2 p0 = { (f16)va.x, (f16)vb.x };
    h2 p1 = { (f16)va.y, (f16)vb.y };
    h2 p2 = { (f16)va.z, (f16)vb.z };
    h2 p3 = { (f16)va.w, (f16)vb.w };
    *(h2*)&t[lq * 4 + 0][cc] = p0;
    *(h2*)&t[lq * 4 + 1][cc] = p1;
    *(h2*)&t[lq * 4 + 2][cc] = p2;
    *(h2*)&t[lq * 4 + 3][cc] = p3;
  }
  __syncthreads();

  int row = tid >> 2, sub = tid & 3;
  h4 r0 = *(const h4*)&t[row][sub * 8];
  h4 r1 = *(const h4*)&t[row][sub * 8 + 4];
  h4 r2 = *(const h4*)&t[row][32 + sub * 8];
  h4 r3 = *(const h4*)&t[row][32 + sub * 8 + 4];
  f16* xo = Xt + ((size_t)b * Ln + l0 + row) * Cn + c0;
  union { h4 h[2]; h8 v; } u0, u1;
  u0.h[0] = r0; u0.h[1] = r1;
  u1.h[0] = r2; u1.h[1] = r3;
  *(h8*)(xo + sub * 8) = u0.v;
  *(h8*)(xo + 32 + sub * 8) = u1.v;
}

// ---------------- kernel 2: projection GEMM, reg-staged double buffer ----------------
__global__ __launch_bounds__(256) void k_proj(const float* __restrict__ Wq,
                                              const float* __restrict__ Wm,
                                              const f16* __restrict__ Xt,
                                              f16* __restrict__ Qd,
                                              f16* __restrict__ Kd,
                                              f16* __restrict__ Vv) {
  int bid = blockIdx.x;
  int b = bid / 384;
  int r = bid % 384;
  int mt = r >> 5, nt = r & 31;
  int o0 = mt << 7, l0 = nt << 7;
  __shared__ f16 a_lds[128][40];
  __shared__ f16 b_lds[128][40];
  int tid = threadIdx.x;
  int lane = tid & 63, w = tid >> 6;
  int wr = w >> 1, wc = w & 1;
  f32x4 acc[4][4] = {};

  int sr = tid >> 1;
  int scg = (tid & 1) << 4;
  int o_s = o0 + sr;
  const float* wrow = (o_s < 512) ? (Wq + (size_t)o_s * Cn)
                                  : (Wm + (size_t)(o_s - 512) * Cn);
  const f16* xrow = Xt + ((size_t)b * Ln + l0 + sr) * Cn;

  float4 wa[4];
  h8 xbr[2];
#pragma unroll
  for (int i = 0; i < 4; ++i) wa[i] = *(const float4*)(wrow + scg + 4 * i);
#pragma unroll
  for (int i = 0; i < 2; ++i) xbr[i] = *(const h8*)(xrow + scg + 8 * i);

  for (int kt = 0; kt < 16; ++kt) {
    __syncthreads();
#pragma unroll
    for (int i = 0; i < 4; ++i) {
      float4 w4 = wa[i];
      h4 hh = { (f16)w4.x, (f16)w4.y, (f16)w4.z, (f16)w4.w };
      *(h4*)&a_lds[sr][scg + 4 * i] = hh;
    }
#pragma unroll
    for (int i = 0; i < 2; ++i)
      *(h8*)&b_lds[sr][scg + 8 * i] = xbr[i];
    if (kt < 15) {
      int c1 = (kt + 1) << 5;
#pragma unroll
      for (int i = 0; i < 4; ++i) wa[i] = *(const float4*)(wrow + c1 + scg + 4 * i);
#pragma unroll
      for (int i = 0; i < 2; ++i) xbr[i] = *(const h8*)(xrow + c1 + scg + 8 * i);
    }
    __syncthreads();

    h8 af[4], bf[4];
#pragma unroll
    for (int mi = 0; mi < 4; ++mi)
      af[mi] = *(const h8*)&a_lds[wr * 64 + mi * 16 + (lane & 15)][(lane >> 4) * 8];
#pragma unroll
    for (int ni = 0; ni < 4; ++ni)
      bf[ni] = *(const h8*)&b_lds[wc * 64 + ni * 16 + (lane & 15)][(lane >> 4) * 8];
#pragma unroll
    for (int mi = 0; mi < 4; ++mi)
#pragma unroll
      for (int ni = 0; ni < 4; ++ni)
        acc[mi][ni] = MFMA32(af[mi], bf[ni], acc[mi][ni]);
  }

  const float QSCALE = 0.18033688011112042f;   // 2^-3 * log2(e)
  int lrow = (lane >> 4) << 2;
  int lcol = lane & 15;
#pragma unroll
  for (int mi = 0; mi < 4; ++mi) {
    int ob = o0 + wr * 64 + mi * 16 + lrow;
#pragma unroll
    for (int ni = 0; ni < 4; ++ni) {
      int lc = l0 + wc * 64 + ni * 16 + lcol;
      f32x4 a = acc[mi][ni];
      if (ob < 512) {
        int h = ob >> 6, d = ob & 63;
        h4 hh = { (f16)(a[0] * QSCALE), (f16)(a[1] * QSCALE),
                  (f16)(a[2] * QSCALE), (f16)(a[3] * QSCALE) };
        *(h4*)&Qd[(((size_t)b * Hn + h) * Ln + lc) * Dn + d] = hh;
      } else if (ob < 1024) {
        int oc = ob - 512;
        int h = oc >> 6, d = oc & 63;
        h4 hh = { (f16)a[0], (f16)a[1], (f16)a[2], (f16)a[3] };
        *(h4*)&Kd[(((size_t)b * Hn + h) * Ln + lc) * Dn + d] = hh;
      } else {
        int oc = ob - 1024;
#pragma unroll
        for (int rr = 0; rr < 4; ++rr)
          Vv[((size_t)b * Cn + oc + rr) * Ln + lc] = (f16)a[rr];
      }
    }
  }
}

// ---------------- kernel 3: flash attention, phase-staggered groups (R11 best: 108.5 us) ----------------
// grid 512 (XCD-swizzled), block = 8 waves, 2 KV-split groups, 2-deep LDS dbuf.
// Group 0 body: QK(t) -> SM_PV(t). Group 1 body: SM_PV(t-1) -> QK(t) (carries S).
// ALL staging strictly post-barrier (R10 race lesson: 2-deep parity (t+1)&1 == (t-1)&1).
__global__ __launch_bounds__(512, 4) void k_attn(const f16* __restrict__ Qd,
                                                 const f16* __restrict__ Kd,
                                                 const f16* __restrict__ Vv,
                                                 const int* __restrict__ mask,
                                                 float* __restrict__ out) {
  int bid0 = blockIdx.x;
  int bid = (bid0 & 7) * 64 + (bid0 >> 3);   // T1: 64 blocks (2 bh) per XCD
  int bh = bid >> 5, ib = bid & 31;
  int b = bh >> 3, h = bh & 7;
  int tid = threadIdx.x;
  int lane = tid & 63, w = tid >> 6;
  int grp = w >> 2, wq = w & 3;
  int il = lane & 31, hi = lane >> 5;

  __shared__ __align__(16) f16 smem[8 * 4096];
#define KBUF(g, bi) (&smem[(((g) * 2 + (bi))) * 4096])
#define VBUF(g, bi) (&smem[((4 + (g) * 2 + (bi))) * 4096])

  int qb = ib * 128 + wq * 32;
  const f16* qp = Qd + ((size_t)bh * Ln + qb + il) * Dn;
  h8 qreg[4];
#pragma unroll
  for (int dt = 0; dt < 4; ++dt)
    qreg[dt] = *(const h8*)(qp + dt * 16 + hi * 8);

  const int* mbase = mask + (size_t)b * Ln;
  unsigned long long flags;
  {
    const int4* mp = (const int4*)mbase + lane * 16;
    int ac = 1;
#pragma unroll
    for (int q = 0; q < 16; ++q) { int4 v = mp[q]; ac &= v.x & v.y & v.z & v.w; }
    flags = __ballot(ac == 1);
  }

  const f16* kbase = Kd + (size_t)bh * Ln * Dn + (size_t)grp * 32 * 4096;
  const f16* vbase = Vv + ((size_t)b * Cn + h * 64) * Ln + grp * 32 * 64;
  int koff[2], voff[2];
#pragma unroll
  for (int q = 0; q < 2; ++q) {
    int rr = wq * 16 + q * 8 + (lane >> 3);
    int swz = (lane & 7) ^ (rr & 7);
    koff[q] = rr * 64 + swz * 8;
    voff[q] = rr * Ln + swz * 8;
  }

#define STAGE_K(bi, t)                                                          \
  {                                                                             \
    _Pragma("unroll")                                                           \
    for (int q = 0; q < 2; ++q)                                                 \
      __builtin_amdgcn_global_load_lds(AS1(kbase + (size_t)(t) * 4096 + koff[q]),\
                                       AS3(KBUF(grp, bi) + (wq * 16 + q * 8) * 64),\
                                       16, 0, 0);                               \
  }
#define STAGE_V(bi, t)                                                          \
  {                                                                             \
    _Pragma("unroll")                                                           \
    for (int q = 0; q < 2; ++q)                                                 \
      __builtin_amdgcn_global_load_lds(AS1(vbase + (size_t)(t) * 64 + voff[q]), \
                                       AS3(VBUF(grp, bi) + (wq * 16 + q * 8) * 64),\
                                       16, 0, 0);                               \
  }

#define PACK_PB(S0_, S1_, DW0_, DW1_, PB_)                                      \
  {                                                                             \
    _Pragma("unroll")                                                           \
    for (int r = 0; r < 16; r += 2) {                                           \
      DW0_[r >> 1] = __builtin_bit_cast(float,                                  \
          __builtin_amdgcn_cvt_pkrtz(S0_[r], S0_[r + 1]));                      \
      DW1_[r >> 1] = __builtin_bit_cast(float,                                  \
          __builtin_amdgcn_cvt_pkrtz(S1_[r], S1_[r + 1]));                      \
    }                                                                           \
    _Pragma("unroll")                                                           \
    for (int jt = 0; jt < 4; ++jt) {                                            \
      float* dd = (jt < 2) ? DW0_ : DW1_;                                       \
      int base = (jt & 1) * 4;                                                  \
      float a0 = dd[base + 0], b0 = dd[base + 2];                               \
      float a1 = dd[base + 1], b1 = dd[base + 3];                               \
      asm("v_permlane32_swap_b32 %0, %1" : "+v"(a0), "+v"(b0));                 \
      asm("v_permlane32_swap_b32 %0, %1" : "+v"(a1), "+v"(b1));                 \
      union { h8 v; float f[4]; } u;                                            \
      u.f[0] = a0; u.f[1] = a1; u.f[2] = b0; u.f[3] = b1;                       \
      PB_[jt] = u.v;                                                            \
    }                                                                           \
  }

  f32x16 acc0 = {}, acc1 = {};  // O^T: col=i=il, row d = dt*32 + (r&3)+8*(r>>2)+4*hi
  float mrow = 0.f;             // fixed base point; bumped only by overflow gate
  float lsum = 0.f;             // half-row sum (merged across hi at epilogue)
  int swz7 = il & 7;

// QK(t): 8 MFMA on K(t) -> S regs (mask fix folded in)
#define QK(t_, S0_, S1_)                                                        \
  {                                                                             \
    const f16* kl_ = KBUF(grp, (t_) & 1);                                       \
    f32x16 z0 = {}, z1 = {};                                                    \
    __builtin_amdgcn_s_setprio(1);                                              \
    _Pragma("unroll")                                                           \
    for (int dt = 0; dt < 4; ++dt) {                                            \
      int c = ((dt * 2 + hi) ^ swz7) << 3;                                      \
      h8 ak0 = *(const h8*)&kl_[il * 64 + c];                                   \
      h8 ak1 = *(const h8*)&kl_[(32 + il) * 64 + c];                            \
      z0 = MFMA3216(ak0, qreg[dt], z0);                                         \
      z1 = MFMA3216(ak1, qreg[dt], z1);                                         \
    }                                                                           \
    __builtin_amdgcn_s_setprio(0);                                              \
    int T_ = grp * 32 + (t_);                                                   \
    if (!((flags >> T_) & 1)) {                                                 \
      _Pragma("unroll")                                                         \
      for (int r = 0; r < 16; ++r) {                                            \
        int j = T_ * 64 + (r & 3) + 8 * (r >> 2) + 4 * hi;                      \
        if (!mbase[j])      z0[r] = -3.0e4f;                                    \
        if (!mbase[j + 32]) z1[r] = -3.0e4f;                                    \
      }                                                                         \
    }                                                                           \
    S0_ = z0; S1_ = z1;                                                         \
  }

// SM_PV(t): softmax on S, then PV on V(t). Consumes S.
#define SM_PV(t_, S0_, S1_)                                                     \
  {                                                                             \
    _Pragma("unroll")                                                           \
    for (int r = 0; r < 16; ++r) {                                              \
      S0_[r] = __builtin_amdgcn_exp2f(S0_[r] - mrow);                           \
      S1_[r] = __builtin_amdgcn_exp2f(S1_[r] - mrow);                           \
    }                                                                           \
    float dw0[8], dw1[8];                                                       \
    h8 pb[4];                                                                   \
    PACK_PB(S0_, S1_, dw0, dw1, pb);                                            \
    float rs;                                                                   \
    {                                                                           \
      float a0 = (S0_[0] + S0_[1]) + (S0_[2] + S0_[3]);                         \
      float a1 = (S0_[4] + S0_[5]) + (S0_[6] + S0_[7]);                         \
      float a2 = (S0_[8] + S0_[9]) + (S0_[10] + S0_[11]);                       \
      float a3 = (S0_[12] + S0_[13]) + (S0_[14] + S0_[15]);                     \
      float a4 = (S1_[0] + S1_[1]) + (S1_[2] + S1_[3]);                         \
      float a5 = (S1_[4] + S1_[5]) + (S1_[6] + S1_[7]);                         \
      float a6 = (S1_[8] + S1_[9]) + (S1_[10] + S1_[11]);                       \
      float a7 = (S1_[12] + S1_[13]) + (S1_[14] + S1_[15]);                     \
      rs = ((a0 + a1) + (a2 + a3)) + ((a4 + a5) + (a6 + a7));                   \
    }                                                                           \
    if (__any(rs > 8192.f)) {  /* overflow gate: ~never, exact pow2 rescale */  \
      float mxp = fmaxf(                                                        \
        fmaxf(fmaxf(fmaxf(S0_[0], S0_[1]), fmaxf(S0_[2], S0_[3])),              \
              fmaxf(fmaxf(S0_[4], S0_[5]), fmaxf(S0_[6], S0_[7]))),             \
        fmaxf(fmaxf(fmaxf(S0_[8], S0_[9]), fmaxf(S0_[10], S0_[11])),            \
              fmaxf(fmaxf(S0_[12], S0_[13]), fmaxf(S0_[14], S0_[15]))));        \
      float mxq = fmaxf(                                                        \
        fmaxf(fmaxf(fmaxf(S1_[0], S1_[1]), fmaxf(S1_[2], S1_[3])),              \
              fmaxf(fmaxf(S1_[4], S1_[5]), fmaxf(S1_[6], S1_[7]))),             \
        fmaxf(fmaxf(fmaxf(S1_[8], S1_[9]), fmaxf(S1_[10], S1_[11])),            \
              fmaxf(fmaxf(S1_[12], S1_[13]), fmaxf(S1_[14], S1_[15]))));        \
      mxp = fmaxf(mxp, mxq);                                                    \
      mxp = fmaxf(mxp, __shfl_xor(mxp, 32));                                    \
      int e = (((__builtin_bit_cast(int, mxp) >> 23) & 255) - 127) - 3;         \
      float sc = __builtin_bit_cast(float, (127 - e) << 23);  /* 2^-e exact */  \
      mrow += (float)e;                                                         \
      _Pragma("unroll")                                                         \
      for (int r = 0; r < 16; ++r) {                                            \
        S0_[r] *= sc; S1_[r] *= sc;                                             \
        acc0[r] *= sc; acc1[r] *= sc;                                           \
      }                                                                         \
      lsum *= sc; rs *= sc;                                                     \
      PACK_PB(S0_, S1_, dw0, dw1, pb);                                          \
    }                                                                           \
    lsum += rs;                                                                 \
    const f16* vl_ = VBUF(grp, (t_) & 1);                                       \
    __builtin_amdgcn_s_setprio(1);                                              \
    _Pragma("unroll")                                                           \
    for (int dt = 0; dt < 2; ++dt) {                                            \
      int rv = dt * 32 + il;                                                    \
      _Pragma("unroll")                                                         \
      for (int jt = 0; jt < 4; ++jt) {                                          \
        h8 av = *(const h8*)&vl_[rv * 64 + (((jt * 2 + hi) ^ swz7) << 3)];      \
        if (dt == 0) acc0 = MFMA3216(av, pb[jt], acc0);                         \
        else         acc1 = MFMA3216(av, pb[jt], acc1);                         \
      }                                                                         \
    }                                                                           \
    __builtin_amdgcn_s_setprio(0);                                              \
  }

#define VM(n) asm volatile("s_waitcnt vmcnt(" n ")" ::: "memory")
#define BAR() __builtin_amdgcn_s_barrier()

  f32x16 sP0, sP1;

  if (grp == 0) {
    // ---- group 0: QK(t) then SM_PV(t); stage K(t+2),V(t+2) post-barrier. ----
    STAGE_K(0, 0); STAGE_V(0, 0);
    STAGE_K(1, 1); STAGE_V(1, 1);
    for (int t = 0; t < 31; ++t) {
      VM("4"); BAR();
      QK(t, sP0, sP1);
      SM_PV(t, sP0, sP1);
      BAR();
      if (t < 30) { STAGE_K(t & 1, t + 2); STAGE_V(t & 1, t + 2); }
    }
    VM("0"); BAR();
    QK(31, sP0, sP1);
    SM_PV(31, sP0, sP1);
    BAR();
  } else {
    // ---- group 1: SM_PV(t-1) then QK(t); ALL stages post-barrier. ----
    STAGE_V(0, 0); STAGE_K(0, 0);
    STAGE_V(1, 1); STAGE_K(1, 1);
    // body 0 (no SM_PV yet): need K(0) -> oldest 4 of {V0,K0,V1,K1}
    VM("4"); BAR();
    QK(0, sP0, sP1);
    BAR();
    STAGE_K(0, 2);
    // body 1: need V(0),K(1) -> leave only K(2) in flight
    VM("2"); BAR();
    SM_PV(0, sP0, sP1);
    QK(1, sP0, sP1);
    BAR();
    STAGE_K(1, 3); STAGE_V(0, 2);
    // bodies 2..30: need K(t),V(t-1); in flight also K(t+1),V(t)
    for (int t = 2; t <= 30; ++t) {
      VM("4"); BAR();
      SM_PV(t - 1, sP0, sP1);
      QK(t, sP0, sP1);
      BAR();
      if (t < 30) STAGE_K(t & 1, t + 2);
      STAGE_V((t + 1) & 1, t + 1);
    }
    // body 31: need K(31),V(30); leave V(31) in flight
    VM("2"); BAR();
    SM_PV(30, sP0, sP1);
    QK(31, sP0, sP1);
    BAR();
    VM("0");
    SM_PV(31, sP0, sP1);
  }

  // full-row lsum (lanes i and i+32 hold halves)
  lsum += __shfl_xor(lsum, 32);

  // ---- merge the two KV halves via LDS (padded stride-33) ----
  __syncthreads();
  float* shf = (float*)smem;
  if (grp == 1) {
    float* basep = shf + wq * (64 * 33) + lane * 33;
#pragma unroll
    for (int r = 0; r < 16; ++r) { basep[r] = acc0[r]; basep[16 + r] = acc1[r]; }
    float* ml = shf + 4 * 64 * 33 + (wq * 64 + lane) * 2;
    ml[0] = mrow; ml[1] = lsum;
  }
  __syncthreads();
  if (grp == 0) {
    float* basep = shf + wq * (64 * 33) + lane * 33;
    float* ml = shf + 4 * 64 * 33 + (wq * 64 + lane) * 2;
    float mB = ml[0], lB = ml[1];
    float M = fmaxf(mrow, mB);
    float wA = __builtin_amdgcn_exp2f(mrow - M);
    float wB = __builtin_amdgcn_exp2f(mB - M);
    float linv = 1.f / fmaxf(lsum * wA + lB * wB, 1e-30f);
    float fA = wA * linv, fB = wB * linv;
    size_t obase = ((size_t)b * Cn + h * 64) * Ln + qb + il;
#pragma unroll
    for (int r = 0; r < 16; ++r) {
      int d0 = (r & 3) + 8 * (r >> 2) + 4 * hi;
      out[obase + (size_t)d0 * Ln] = acc0[r] * fA + basep[r] * fB;
      out[obase + (size_t)(d0 + 32) * Ln] = acc1[r] * fA + basep[16 + r] * fB;
    }
  }
}

extern "C" void kernel_launch(void* const* d_in, const int* in_sizes, int n_in,
                              void* d_out, int out_size, void* d_ws, size_t ws_size,
                              hipStream_t stream) {
  const float* queries = (const float*)d_in[0];
  const int*   mask    = (const int*)d_in[1];
  const float* Wm      = (const float*)d_in[2];
  const float* Wq      = (const float*)d_in[3];
  float* out = (float*)d_out;
  char* ws = (char*)d_ws;
  f16* Xt = (f16*)(ws);
  f16* Qd = (f16*)(ws + 8388608);
  f16* Kd = (f16*)(ws + 16777216);
  f16* Vv = (f16*)(ws + 25165824);

  k_transpose<<<1024, 256, 0, stream>>>(queries, Xt);
  k_proj<<<768, 256, 0, stream>>>(Wq, Wm, Xt, Qd, Kd, Vv);
  k_attn<<<512, 512, 0, stream>>>(Qd, Kd, Vv, mask, out);
}

// Round 17
// 132.020 us; speedup vs baseline: 1.0763x; 1.0045x over previous
//
#include <hip/hip_runtime.h>

#define Bn 2
#define Cn 512
#define Ln 4096
#define Hn 8
#define Dn 64

typedef _Float16 f16;
typedef _Float16 h8 __attribute__((ext_vector_type(8)));
typedef _Float16 h4 __attribute__((ext_vector_type(4)));
typedef _Float16 h2 __attribute__((ext_vector_type(2)));
typedef float f32x4 __attribute__((ext_vector_type(4)));
typedef float f32x16 __attribute__((ext_vector_type(16)));

#define MFMA32(a, b, c) __builtin_amdgcn_mfma_f32_16x16x32_f16(a, b, c, 0, 0, 0)
#define MFMA3216(a, b, c) __builtin_amdgcn_mfma_f32_32x32x16_f16(a, b, c, 0, 0, 0)
#define AS1(p) ((const __attribute__((address_space(1))) void*)(p))
#define AS3(p) ((__attribute__((address_space(3))) void*)(p))

// ---------------- kernel 1: fused projection GEMM (transpose folded into B-staging) ----------------
// B-tile read straight from X[b][c][l] f32: 2 c-rows x 8 l per thread (4x float4,
// coalesced), transposed into b_lds via full-dword h2 writes. [128][42] odd-stride pad.
__global__ __launch_bounds__(256) void k_proj(const float* __restrict__ Wq,
                                              const float* __restrict__ Wm,
                                              const float* __restrict__ X,
                                              f16* __restrict__ Qd,
                                              f16* __restrict__ Kd,
                                              f16* __restrict__ Vv) {
  int bid = blockIdx.x;
  int b = bid / 384;
  int r = bid % 384;
  int mt = r >> 5, nt = r & 31;
  int o0 = mt << 7, l0 = nt << 7;
  __shared__ f16 a_lds[128][40];
  __shared__ f16 b_lds[128][42];   // 21-dword row stride (odd): b128 reads conflict-free
  int tid = threadIdx.x;
  int lane = tid & 63, w = tid >> 6;
  int wr = w >> 1, wc = w & 1;
  f32x4 acc[4][4] = {};

  // A-staging (weights f32 -> f16), reg double-buffered (unchanged)
  int sr = tid >> 1;
  int scg = (tid & 1) << 4;
  int o_s = o0 + sr;
  const float* wrow = (o_s < 512) ? (Wq + (size_t)o_s * Cn)
                                  : (Wm + (size_t)(o_s - 512) * Cn);

  // B-staging from X: thread owns c-pair (2*ccp) and 8 l's (lq*8)
  int ccp = tid >> 4;              // 0..15
  int lq  = tid & 15;              // 0..15
  const float* xrow0 = X + ((size_t)b * Cn + 2 * ccp) * Ln + l0 + lq * 8;

  float4 wa[4];
  float4 xa0, xa1, xc0, xc1;
#pragma unroll
  for (int i = 0; i < 4; ++i) wa[i] = *(const float4*)(wrow + scg + 4 * i);
  {
    const float* p0 = xrow0;           // c = 2*ccp (kt=0)
    const float* p1 = xrow0 + Ln;      // c = 2*ccp+1
    xa0 = *(const float4*)(p0);
    xa1 = *(const float4*)(p0 + 4);
    xc0 = *(const float4*)(p1);
    xc1 = *(const float4*)(p1 + 4);
  }

  for (int kt = 0; kt < 16; ++kt) {
    __syncthreads();                 // previous iter's frag reads done
#pragma unroll
    for (int i = 0; i < 4; ++i) {
      float4 w4 = wa[i];
      h4 hh = { (f16)w4.x, (f16)w4.y, (f16)w4.z, (f16)w4.w };
      *(h4*)&a_lds[sr][scg + 4 * i] = hh;
    }
    {
      const float* a0 = (const float*)&xa0;
      const float* a1 = (const float*)&xa1;
      const float* c0p = (const float*)&xc0;
      const float* c1p = (const float*)&xc1;
#pragma unroll
      for (int j = 0; j < 4; ++j) {
        h2 p = { (f16)a0[j], (f16)c0p[j] };
        *(h2*)&b_lds[lq * 8 + j][ccp * 2] = p;
        h2 q = { (f16)a1[j], (f16)c1p[j] };
        *(h2*)&b_lds[lq * 8 + 4 + j][ccp * 2] = q;
      }
    }
    if (kt < 15) {                   // prefetch next k-tile; flies during MFMAs
      int c1 = (kt + 1) << 5;
#pragma unroll
      for (int i = 0; i < 4; ++i) wa[i] = *(const float4*)(wrow + c1 + scg + 4 * i);
      const float* p0 = xrow0 + (size_t)c1 * Ln;
      const float* p1 = p0 + Ln;
      xa0 = *(const float4*)(p0);
      xa1 = *(const float4*)(p0 + 4);
      xc0 = *(const float4*)(p1);
      xc1 = *(const float4*)(p1 + 4);
    }
    __syncthreads();                 // LDS tile ready

    h8 af[4], bf[4];
#pragma unroll
    for (int mi = 0; mi < 4; ++mi)
      af[mi] = *(const h8*)&a_lds[wr * 64 + mi * 16 + (lane & 15)][(lane >> 4) * 8];
#pragma unroll
    for (int ni = 0; ni < 4; ++ni)
      bf[ni] = *(const h8*)&b_lds[wc * 64 + ni * 16 + (lane & 15)][(lane >> 4) * 8];
#pragma unroll
    for (int mi = 0; mi < 4; ++mi)
#pragma unroll
      for (int ni = 0; ni < 4; ++ni)
        acc[mi][ni] = MFMA32(af[mi], bf[ni], acc[mi][ni]);
  }

  const float QSCALE = 0.18033688011112042f;   // 2^-3 * log2(e)
  int lrow = (lane >> 4) << 2;
  int lcol = lane & 15;
#pragma unroll
  for (int mi = 0; mi < 4; ++mi) {
    int ob = o0 + wr * 64 + mi * 16 + lrow;
#pragma unroll
    for (int ni = 0; ni < 4; ++ni) {
      int lc = l0 + wc * 64 + ni * 16 + lcol;
      f32x4 a = acc[mi][ni];
      if (ob < 512) {
        int h = ob >> 6, d = ob & 63;
        h4 hh = { (f16)(a[0] * QSCALE), (f16)(a[1] * QSCALE),
                  (f16)(a[2] * QSCALE), (f16)(a[3] * QSCALE) };
        *(h4*)&Qd[(((size_t)b * Hn + h) * Ln + lc) * Dn + d] = hh;
      } else if (ob < 1024) {
        int oc = ob - 512;
        int h = oc >> 6, d = oc & 63;
        h4 hh = { (f16)a[0], (f16)a[1], (f16)a[2], (f16)a[3] };
        *(h4*)&Kd[(((size_t)b * Hn + h) * Ln + lc) * Dn + d] = hh;
      } else {
        int oc = ob - 1024;
#pragma unroll
        for (int rr = 0; rr < 4; ++rr)
          Vv[((size_t)b * Cn + oc + rr) * Ln + lc] = (f16)a[rr];
      }
    }
  }
}

// ---------------- kernel 2: flash attention, phase-staggered groups (R11 best: 108.5 us) ----------------
// grid 512 (XCD-swizzled), block = 8 waves, 2 KV-split groups, 2-deep LDS dbuf.
// Group 0 body: QK(t) -> SM_PV(t). Group 1 body: SM_PV(t-1) -> QK(t) (carries S).
// ALL staging strictly post-barrier (R10 race lesson: 2-deep parity (t+1)&1 == (t-1)&1).
__global__ __launch_bounds__(512, 4) void k_attn(const f16* __restrict__ Qd,
                                                 const f16* __restrict__ Kd,
                                                 const f16* __restrict__ Vv,
                                                 const int* __restrict__ mask,
                                                 float* __restrict__ out) {
  int bid0 = blockIdx.x;
  int bid = (bid0 & 7) * 64 + (bid0 >> 3);   // T1: 64 blocks (2 bh) per XCD
  int bh = bid >> 5, ib = bid & 31;
  int b = bh >> 3, h = bh & 7;
  int tid = threadIdx.x;
  int lane = tid & 63, w = tid >> 6;
  int grp = w >> 2, wq = w & 3;
  int il = lane & 31, hi = lane >> 5;

  __shared__ __align__(16) f16 smem[8 * 4096];
#define KBUF(g, bi) (&smem[(((g) * 2 + (bi))) * 4096])
#define VBUF(g, bi) (&smem[((4 + (g) * 2 + (bi))) * 4096])

  int qb = ib * 128 + wq * 32;
  const f16* qp = Qd + ((size_t)bh * Ln + qb + il) * Dn;
  h8 qreg[4];
#pragma unroll
  for (int dt = 0; dt < 4; ++dt)
    qreg[dt] = *(const h8*)(qp + dt * 16 + hi * 8);

  const int* mbase = mask + (size_t)b * Ln;
  unsigned long long flags;
  {
    const int4* mp = (const int4*)mbase + lane * 16;
    int ac = 1;
#pragma unroll
    for (int q = 0; q < 16; ++q) { int4 v = mp[q]; ac &= v.x & v.y & v.z & v.w; }
    flags = __ballot(ac == 1);
  }

  const f16* kbase = Kd + (size_t)bh * Ln * Dn + (size_t)grp * 32 * 4096;
  const f16* vbase = Vv + ((size_t)b * Cn + h * 64) * Ln + grp * 32 * 64;
  int koff[2], voff[2];
#pragma unroll
  for (int q = 0; q < 2; ++q) {
    int rr = wq * 16 + q * 8 + (lane >> 3);
    int swz = (lane & 7) ^ (rr & 7);
    koff[q] = rr * 64 + swz * 8;
    voff[q] = rr * Ln + swz * 8;
  }

#define STAGE_K(bi, t)                                                          \
  {                                                                             \
    _Pragma("unroll")                                                           \
    for (int q = 0; q < 2; ++q)                                                 \
      __builtin_amdgcn_global_load_lds(AS1(kbase + (size_t)(t) * 4096 + koff[q]),\
                                       AS3(KBUF(grp, bi) + (wq * 16 + q * 8) * 64),\
                                       16, 0, 0);                               \
  }
#define STAGE_V(bi, t)                                                          \
  {                                                                             \
    _Pragma("unroll")                                                           \
    for (int q = 0; q < 2; ++q)                                                 \
      __builtin_amdgcn_global_load_lds(AS1(vbase + (size_t)(t) * 64 + voff[q]), \
                                       AS3(VBUF(grp, bi) + (wq * 16 + q * 8) * 64),\
                                       16, 0, 0);                               \
  }

#define PACK_PB(S0_, S1_, DW0_, DW1_, PB_)                                      \
  {                                                                             \
    _Pragma("unroll")                                                           \
    for (int r = 0; r < 16; r += 2) {                                           \
      DW0_[r >> 1] = __builtin_bit_cast(float,                                  \
          __builtin_amdgcn_cvt_pkrtz(S0_[r], S0_[r + 1]));                      \
      DW1_[r >> 1] = __builtin_bit_cast(float,                                  \
          __builtin_amdgcn_cvt_pkrtz(S1_[r], S1_[r + 1]));                      \
    }                                                                           \
    _Pragma("unroll")                                                           \
    for (int jt = 0; jt < 4; ++jt) {                                            \
      float* dd = (jt < 2) ? DW0_ : DW1_;                                       \
      int base = (jt & 1) * 4;                                                  \
      float a0 = dd[base + 0], b0 = dd[base + 2];                               \
      float a1 = dd[base + 1], b1 = dd[base + 3];                               \
      asm("v_permlane32_swap_b32 %0, %1" : "+v"(a0), "+v"(b0));                 \
      asm("v_permlane32_swap_b32 %0, %1" : "+v"(a1), "+v"(b1));                 \
      union { h8 v; float f[4]; } u;                                            \
      u.f[0] = a0; u.f[1] = a1; u.f[2] = b0; u.f[3] = b1;                       \
      PB_[jt] = u.v;                                                            \
    }                                                                           \
  }

  f32x16 acc0 = {}, acc1 = {};  // O^T: col=i=il, row d = dt*32 + (r&3)+8*(r>>2)+4*hi
  float mrow = 0.f;             // fixed base point; bumped only by overflow gate
  float lsum = 0.f;             // half-row sum (merged across hi at epilogue)
  int swz7 = il & 7;

// QK(t): 8 MFMA on K(t) -> S regs (mask fix folded in)
#define QK(t_, S0_, S1_)                                                        \
  {                                                                             \
    const f16* kl_ = KBUF(grp, (t_) & 1);                                       \
    f32x16 z0 = {}, z1 = {};                                                    \
    __builtin_amdgcn_s_setprio(1);                                              \
    _Pragma("unroll")                                                           \
    for (int dt = 0; dt < 4; ++dt) {                                            \
      int c = ((dt * 2 + hi) ^ swz7) << 3;                                      \
      h8 ak0 = *(const h8*)&kl_[il * 64 + c];                                   \
      h8 ak1 = *(const h8*)&kl_[(32 + il) * 64 + c];                            \
      z0 = MFMA3216(ak0, qreg[dt], z0);                                         \
      z1 = MFMA3216(ak1, qreg[dt], z1);                                         \
    }                                                                           \
    __builtin_amdgcn_s_setprio(0);                                              \
    int T_ = grp * 32 + (t_);                                                   \
    if (!((flags >> T_) & 1)) {                                                 \
      _Pragma("unroll")                                                         \
      for (int r = 0; r < 16; ++r) {                                            \
        int j = T_ * 64 + (r & 3) + 8 * (r >> 2) + 4 * hi;                      \
        if (!mbase[j])      z0[r] = -3.0e4f;                                    \
        if (!mbase[j + 32]) z1[r] = -3.0e4f;                                    \
      }                                                                         \
    }                                                                           \
    S0_ = z0; S1_ = z1;                                                         \
  }

// SM_PV(t): softmax on S, then PV on V(t). Consumes S.
#define SM_PV(t_, S0_, S1_)                                                     \
  {                                                                             \
    _Pragma("unroll")                                                           \
    for (int r = 0; r < 16; ++r) {                                              \
      S0_[r] = __builtin_amdgcn_exp2f(S0_[r] - mrow);                           \
      S1_[r] = __builtin_amdgcn_exp2f(S1_[r] - mrow);                           \
    }                                                                           \
    float dw0[8], dw1[8];                                                       \
    h8 pb[4];                                                                   \
    PACK_PB(S0_, S1_, dw0, dw1, pb);                                            \
    float rs;                                                                   \
    {                                                                           \
      float a0 = (S0_[0] + S0_[1]) + (S0_[2] + S0_[3]);                         \
      float a1 = (S0_[4] + S0_[5]) + (S0_[6] + S0_[7]);                         \
      float a2 = (S0_[8] + S0_[9]) + (S0_[10] + S0_[11]);                       \
      float a3 = (S0_[12] + S0_[13]) + (S0_[14] + S0_[15]);                     \
      float a4 = (S1_[0] + S1_[1]) + (S1_[2] + S1_[3]);                         \
      float a5 = (S1_[4] + S1_[5]) + (S1_[6] + S1_[7]);                         \
      float a6 = (S1_[8] + S1_[9]) + (S1_[10] + S1_[11]);                       \
      float a7 = (S1_[12] + S1_[13]) + (S1_[14] + S1_[15]);                     \
      rs = ((a0 + a1) + (a2 + a3)) + ((a4 + a5) + (a6 + a7));                   \
    }                                                                           \
    if (__any(rs > 8192.f)) {  /* overflow gate: ~never, exact pow2 rescale */  \
      float mxp = fmaxf(                                                        \
        fmaxf(fmaxf(fmaxf(S0_[0], S0_[1]), fmaxf(S0_[2], S0_[3])),              \
              fmaxf(fmaxf(S0_[4], S0_[5]), fmaxf(S0_[6], S0_[7]))),             \
        fmaxf(fmaxf(fmaxf(S0_[8], S0_[9]), fmaxf(S0_[10], S0_[11])),            \
              fmaxf(fmaxf(S0_[12], S0_[13]), fmaxf(S0_[14], S0_[15]))));        \
      float mxq = fmaxf(                                                        \
        fmaxf(fmaxf(fmaxf(S1_[0], S1_[1]), fmaxf(S1_[2], S1_[3])),              \
              fmaxf(fmaxf(S1_[4], S1_[5]), fmaxf(S1_[6], S1_[7]))),             \
        fmaxf(fmaxf(fmaxf(S1_[8], S1_[9]), fmaxf(S1_[10], S1_[11])),            \
              fmaxf(fmaxf(S1_[12], S1_[13]), fmaxf(S1_[14], S1_[15]))));        \
      mxp = fmaxf(mxp, mxq);                                                    \
      mxp = fmaxf(mxp, __shfl_xor(mxp, 32));                                    \
      int e = (((__builtin_bit_cast(int, mxp) >> 23) & 255) - 127) - 3;         \
      float sc = __builtin_bit_cast(float, (127 - e) << 23);  /* 2^-e exact */  \
      mrow += (float)e;                                                         \
      _Pragma("unroll")                                                         \
      for (int r = 0; r < 16; ++r) {                                            \
        S0_[r] *= sc; S1_[r] *= sc;                                             \
        acc0[r] *= sc; acc1[r] *= sc;                                           \
      }                                                                         \
      lsum *= sc; rs *= sc;                                                     \
      PACK_PB(S0_, S1_, dw0, dw1, pb);                                          \
    }                                                                           \
    lsum += rs;                                                                 \
    const f16* vl_ = VBUF(grp, (t_) & 1);                                       \
    __builtin_amdgcn_s_setprio(1);                                              \
    _Pragma("unroll")                                                           \
    for (int dt = 0; dt < 2; ++dt) {                                            \
      int rv = dt * 32 + il;                                                    \
      _Pragma("unroll")                                                         \
      for (int jt = 0; jt < 4; ++jt) {                                          \
        h8 av = *(const h8*)&vl_[rv * 64 + (((jt * 2 + hi) ^ swz7) << 3)];      \
        if (dt == 0) acc0 = MFMA3216(av, pb[jt], acc0);                         \
        else         acc1 = MFMA3216(av, pb[jt], acc1);                         \
      }                                                                         \
    }                                                                           \
    __builtin_amdgcn_s_setprio(0);                                              \
  }

#define VM(n) asm volatile("s_waitcnt vmcnt(" n ")" ::: "memory")
#define BAR() __builtin_amdgcn_s_barrier()

  f32x16 sP0, sP1;

  if (grp == 0) {
    // ---- group 0: QK(t) then SM_PV(t); stage K(t+2),V(t+2) post-barrier. ----
    STAGE_K(0, 0); STAGE_V(0, 0);
    STAGE_K(1, 1); STAGE_V(1, 1);
    for (int t = 0; t < 31; ++t) {
      VM("4"); BAR();
      QK(t, sP0, sP1);
      SM_PV(t, sP0, sP1);
      BAR();
      if (t < 30) { STAGE_K(t & 1, t + 2); STAGE_V(t & 1, t + 2); }
    }
    VM("0"); BAR();
    QK(31, sP0, sP1);
    SM_PV(31, sP0, sP1);
    BAR();
  } else {
    // ---- group 1: SM_PV(t-1) then QK(t); ALL stages post-barrier. ----
    STAGE_V(0, 0); STAGE_K(0, 0);
    STAGE_V(1, 1); STAGE_K(1, 1);
    // body 0 (no SM_PV yet): need K(0) -> oldest 4 of {V0,K0,V1,K1}
    VM("4"); BAR();
    QK(0, sP0, sP1);
    BAR();
    STAGE_K(0, 2);
    // body 1: need V(0),K(1) -> leave only K(2) in flight
    VM("2"); BAR();
    SM_PV(0, sP0, sP1);
    QK(1, sP0, sP1);
    BAR();
    STAGE_K(1, 3); STAGE_V(0, 2);
    // bodies 2..30: need K(t),V(t-1); in flight also K(t+1),V(t)
    for (int t = 2; t <= 30; ++t) {
      VM("4"); BAR();
      SM_PV(t - 1, sP0, sP1);
      QK(t, sP0, sP1);
      BAR();
      if (t < 30) STAGE_K(t & 1, t + 2);
      STAGE_V((t + 1) & 1, t + 1);
    }
    // body 31: need K(31),V(30); leave V(31) in flight
    VM("2"); BAR();
    SM_PV(30, sP0, sP1);
    QK(31, sP0, sP1);
    BAR();
    VM("0");
    SM_PV(31, sP0, sP1);
  }

  // full-row lsum (lanes i and i+32 hold halves)
  lsum += __shfl_xor(lsum, 32);

  // ---- merge the two KV halves via LDS (padded stride-33) ----
  __syncthreads();
  float* shf = (float*)smem;
  if (grp == 1) {
    float* basep = shf + wq * (64 * 33) + lane * 33;
#pragma unroll
    for (int r = 0; r < 16; ++r) { basep[r] = acc0[r]; basep[16 + r] = acc1[r]; }
    float* ml = shf + 4 * 64 * 33 + (wq * 64 + lane) * 2;
    ml[0] = mrow; ml[1] = lsum;
  }
  __syncthreads();
  if (grp == 0) {
    float* basep = shf + wq * (64 * 33) + lane * 33;
    float* ml = shf + 4 * 64 * 33 + (wq * 64 + lane) * 2;
    float mB = ml[0], lB = ml[1];
    float M = fmaxf(mrow, mB);
    float wA = __builtin_amdgcn_exp2f(mrow - M);
    float wB = __builtin_amdgcn_exp2f(mB - M);
    float linv = 1.f / fmaxf(lsum * wA + lB * wB, 1e-30f);
    float fA = wA * linv, fB = wB * linv;
    size_t obase = ((size_t)b * Cn + h * 64) * Ln + qb + il;
#pragma unroll
    for (int r = 0; r < 16; ++r) {
      int d0 = (r & 3) + 8 * (r >> 2) + 4 * hi;
      out[obase + (size_t)d0 * Ln] = acc0[r] * fA + basep[r] * fB;
      out[obase + (size_t)(d0 + 32) * Ln] = acc1[r] * fA + basep[16 + r] * fB;
    }
  }
}

extern "C" void kernel_launch(void* const* d_in, const int* in_sizes, int n_in,
                              void* d_out, int out_size, void* d_ws, size_t ws_size,
                              hipStream_t stream) {
  const float* queries = (const float*)d_in[0];
  const int*   mask    = (const int*)d_in[1];
  const float* Wm      = (const float*)d_in[2];
  const float* Wq      = (const float*)d_in[3];
  float* out = (float*)d_out;
  char* ws = (char*)d_ws;
  f16* Qd = (f16*)(ws + 8388608);
  f16* Kd = (f16*)(ws + 16777216);
  f16* Vv = (f16*)(ws + 25165824);

  k_proj<<<768, 256, 0, stream>>>(Wq, Wm, queries, Qd, Kd, Vv);
  k_attn<<<512, 512, 0, stream>>>(Qd, Kd, Vv, mask, out);
}